// Round 3
// baseline (1180.983 us; speedup 1.0000x reference)
//
#include <hip/hip_runtime.h>
#include <math.h>
#include <stdint.h>

#define D       128
#define KCODES  1024
#define NQ      8
#define BATCH   8
#define SLEN    4096
#define NPTS    (BATCH*SLEN)     /* 32768 */
#define TM      64               /* points per argmin block */

// async global->LDS, 16B per lane (wave-uniform LDS base + lane*16)
typedef __attribute__((address_space(1))) const void GV;
typedef __attribute__((address_space(3))) void LV;
__device__ __forceinline__ void gload16(const void* g, void* l) {
    __builtin_amdgcn_global_load_lds((GV*)g, (LV*)l, 16, 0, 0);
}

// ---------------- zero scratch ----------------
__global__ void k_zero(int* hist, double* csum) {
    int t = blockIdx.x * blockDim.x + threadIdx.x;
    if (t < NQ * KCODES) hist[t] = 0;
    if (t == 0) *csum = 0.0;
}

// ---------------- codebook norms: numpy pairwise fp32 ----------------
__global__ void k_c2(const float* __restrict__ cbs, float* __restrict__ c2f) {
    int i = blockIdx.x * blockDim.x + threadIdx.x;   // 0..8191
    const float* row = cbs + (size_t)i * D;
    float r8[8];
    #pragma unroll
    for (int j = 0; j < 8; ++j) r8[j] = __fmul_rn(row[j], row[j]);
    for (int d = 8; d < 128; d += 8)
        #pragma unroll
        for (int j = 0; j < 8; ++j)
            r8[j] = __fadd_rn(r8[j], __fmul_rn(row[d + j], row[d + j]));
    float s01 = __fadd_rn(r8[0], r8[1]);
    float s23 = __fadd_rn(r8[2], r8[3]);
    float s45 = __fadd_rn(r8[4], r8[5]);
    float s67 = __fadd_rn(r8[6], r8[7]);
    c2f[i] = __fadd_rn(__fadd_rn(s01, s23), __fadd_rn(s45, s67));
}

// ---------------- init: z [B,D,S] -> resid fp32 [n][d]; quant = 0 ----------------
__global__ __launch_bounds__(256) void k_init(const float* __restrict__ z,
                                              float* __restrict__ resid,
                                              float* __restrict__ quant) {
    __shared__ float xt[64][129];
    int b = blockIdx.x >> 6, st = blockIdx.x & 63;
    int s0 = st * 64;
    for (int it = 0; it < 32; ++it) {
        int flat = it * 256 + threadIdx.x;
        int d = flat >> 6, sl = flat & 63;
        xt[sl][d] = z[((size_t)(b * D + d)) * SLEN + s0 + sl];
    }
    __syncthreads();
    for (int it = 0; it < 8; ++it) {
        int flat = it * 256 + threadIdx.x;
        int sl = flat >> 5, dq = (flat & 31) * 4;
        size_t o = (size_t)(b * SLEN + s0 + sl) * D + dq;
        float4 r;
        r.x = xt[sl][dq]; r.y = xt[sl][dq + 1];
        r.z = xt[sl][dq + 2]; r.w = xt[sl][dq + 3];
        *(float4*)(resid + o) = r;
        float4 zz; zz.x = zz.y = zz.z = zz.w = 0.0f;
        *(float4*)(quant + o) = zz;
    }
}

// ---------------- fp32-emulated argmin (matches numpy/BLAS rounding) ----------------
// Barrier-free wave-private schedule (verified in r2). 4 waves; wave w owns
// codes [256w,256w+256) in 4 chunks of 64. pl=l&7, cl=l>>3; tile 8x8/thread.
// K sliced 16 dims/step; global_load_lds DMA into per-wave 2x4KB double
// buffer; LDS image XOR-swizzled via pre-swizzled global source (conflict-
// free cf reads, SQ_LDS_BANK_CONFLICT==0 measured).
// r3 changes: (1) c2 staged to LDS in prologue -> main-loop vmcnt queue
// holds ONLY slice DMAs; (2) manual 2x t-unroll with compile-time buf, no
// sched_barrier -> compiler schedules FMAs across the DMA issue/wait;
// (3) s_setprio(1) around FMA blocks (wave role diversity, T5).
// Exact fp32 semantics unchanged: per (point,code) single FMA chain over
// dims 0..127 ascending; score fl(fl(xx-2*acc)+cc); first-min (strict <).
__global__ __launch_bounds__(256) void k_argmin(const float* __restrict__ cb,
                                                const float* __restrict__ c2,
                                                const float* __restrict__ resid,
                                                int* __restrict__ idx_out) {
    __shared__ __align__(16) float xs[TM][132];     // 33,792 B
    __shared__ float xxs[TM];
    __shared__ __align__(16) float cs[4][2][1024];  // 32,768 B: [wave][buf][64c x 16d]
    __shared__ __align__(16) float ccl[4][256];     //  4,096 B: per-wave c2
    __shared__ float redS[4][TM];
    __shared__ int   redI[4][TM];

    int tid = threadIdx.x;
    int pbase = blockIdx.x * TM;
    int l = tid & 63, w = tid >> 6;
    int pl = l & 7, cl = l >> 3;

    const char*  cwb = (const char*)cb + ((size_t)w << 17);  // wave's 256 code rows
    const float* c2w = c2 + (w << 8);

    // pre-swizzled per-lane global source offset within one (chunk,slice,g) unit:
    // row l>>2 (+16 per g), fetch dim-chunk (l&3)^tau, tau=((l>>3)&3)==((row>>1)&3)
    int gsrc_lane = ((l >> 2) << 9) + ((((l & 3) ^ ((l >> 3) & 3))) << 4);
    // cf read swizzle: row k'=cl+8j -> tau_row = (cl>>1)&3 (indep of j)
    int rtau = (cl >> 1) & 3;
    char* csw = (char*)&cs[w][0][0];
    const char* xsb = (const char*)&xs[0][0];

    // prologue DMAs: c2 (1 instr, oldest) then slice 0 (4 instrs)
    gload16((const char*)c2w + l * 16, (char*)&ccl[w][0] + l * 16);
    {
        const char* src = cwb + gsrc_lane;
        #pragma unroll
        for (int g = 0; g < 4; ++g)
            gload16(src + (g << 13), csw + (g << 10));
    }

    // stage X tile (fp32 residual), coalesced float4
    #pragma unroll
    for (int it = 0; it < 8; ++it) {
        int e = (it * 256 + tid) * 4;
        int p = e >> 7, d = e & 127;
        *(float4*)&xs[p][d] = *(const float4*)(resid + (size_t)(pbase + p) * D + d);
    }
    __syncthreads();

    // xx per point: numpy pairwise n=128 (8-accumulator pattern)
    if (tid < TM) {
        float r8[8];
        #pragma unroll
        for (int j = 0; j < 8; ++j) r8[j] = __fmul_rn(xs[tid][j], xs[tid][j]);
        for (int i = 8; i < 128; i += 8)
            #pragma unroll
            for (int j = 0; j < 8; ++j)
                r8[j] = __fadd_rn(r8[j], __fmul_rn(xs[tid][i + j], xs[tid][i + j]));
        float s01 = __fadd_rn(r8[0], r8[1]);
        float s23 = __fadd_rn(r8[2], r8[3]);
        float s45 = __fadd_rn(r8[4], r8[5]);
        float s67 = __fadd_rn(r8[6], r8[7]);
        xxs[tid] = __fadd_rn(__fadd_rn(s01, s23), __fadd_rn(s45, s67));
    }
    __syncthreads();

    float xxr[8];
    #pragma unroll
    for (int i = 0; i < 8; ++i) xxr[i] = xxs[pl + 8 * i];

    float acc[8][8];
    #pragma unroll
    for (int i = 0; i < 8; ++i)
        #pragma unroll
        for (int j = 0; j < 8; ++j) acc[i][j] = 0.0f;
    float best[8]; int bidx[8];
    #pragma unroll
    for (int i = 0; i < 8; ++i) { best[i] = 3.4e38f; bidx[i] = 0; }

#define ISSUE(T2) { \
    const char* _src = cwb + gsrc_lane + (((T2) >> 3) << 15) + (((T2) & 7) << 6); \
    char* _dst = csw + (((T2) & 1) << 12); \
    gload16(_src,             _dst);             \
    gload16(_src + (1 << 13), _dst + (1 << 10)); \
    gload16(_src + (2 << 13), _dst + (2 << 10)); \
    gload16(_src + (3 << 13), _dst + (3 << 10)); }

#define COMPUTE(BUF, SS) { \
    const char* cbuf = csw + ((BUF) << 12) + (cl << 6); \
    const char* xrow = xsb + pl * 528 + ((SS) << 6); \
    _Pragma("unroll") \
    for (int d4 = 0; d4 < 4; ++d4) { \
        float4 xf[8], cf[8]; \
        _Pragma("unroll") \
        for (int i = 0; i < 8; ++i) \
            xf[i] = *(const float4*)(xrow + i * 4224 + (d4 << 4)); \
        _Pragma("unroll") \
        for (int j = 0; j < 8; ++j) \
            cf[j] = *(const float4*)(cbuf + ((d4 ^ rtau) << 4) + (j << 9)); \
        _Pragma("unroll") \
        for (int j = 0; j < 8; ++j) \
            _Pragma("unroll") \
            for (int i = 0; i < 8; ++i) { \
                acc[i][j] = __fmaf_rn(xf[i].x, cf[j].x, acc[i][j]); \
                acc[i][j] = __fmaf_rn(xf[i].y, cf[j].y, acc[i][j]); \
                acc[i][j] = __fmaf_rn(xf[i].z, cf[j].z, acc[i][j]); \
                acc[i][j] = __fmaf_rn(xf[i].w, cf[j].w, acc[i][j]); \
            } \
    } }

#define FOLD(CBLK) { \
    _Pragma("unroll") \
    for (int j = 0; j < 8; ++j) { \
        float cc = ccl[w][((CBLK) << 6) + cl + (j << 3)]; \
        int k = (w << 8) + ((CBLK) << 6) + cl + (j << 3); \
        _Pragma("unroll") \
        for (int i = 0; i < 8; ++i) { \
            float t1  = __fadd_rn(xxr[i], __fmul_rn(-2.0f, acc[i][j])); \
            float dsc = __fadd_rn(t1, cc); \
            if (dsc < best[i]) { best[i] = dsc; bidx[i] = k; } \
            acc[i][j] = 0.0f; \
        } \
    } }

    #pragma unroll 1
    for (int tt = 0; tt < 16; ++tt) {        // two slices per iteration
        int cblk = tt >> 2, sA = (tt & 3) << 1;
        // half A: slice t=2tt, buf 0; issue slice 2tt+1 into buf 1
        ISSUE(2 * tt + 1);
        asm volatile("s_waitcnt vmcnt(4)" ::: "memory");   // slice 2tt arrived
        __builtin_amdgcn_s_setprio(1);
        COMPUTE(0, sA);
        __builtin_amdgcn_s_setprio(0);
        // half B: slice t=2tt+1, buf 1; issue slice 2tt+2 into buf 0
        if (tt < 15) {
            ISSUE(2 * tt + 2);
            asm volatile("s_waitcnt vmcnt(4)" ::: "memory");
        } else {
            asm volatile("s_waitcnt vmcnt(0)" ::: "memory");
        }
        __builtin_amdgcn_s_setprio(1);
        COMPUTE(1, sA + 1);
        __builtin_amdgcn_s_setprio(0);
        if ((tt & 3) == 3) FOLD(cblk);       // end of 64-code chunk
    }

    // cross-lane (cl bits 3..5) lexicographic argmin reduce, then cross-wave
    #pragma unroll
    for (int i = 0; i < 8; ++i) {
        float b = best[i]; int bi = bidx[i];
        #pragma unroll
        for (int off = 8; off < 64; off <<= 1) {
            float b2 = __shfl_xor(b, off, 64);
            int  bi2 = __shfl_xor(bi, off, 64);
            if (b2 < b || (b2 == b && bi2 < bi)) { b = b2; bi = bi2; }
        }
        if (cl == 0) { redS[w][pl + 8 * i] = b; redI[w][pl + 8 * i] = bi; }
    }
    __syncthreads();
    if (tid < TM) {
        float b = redS[0][tid]; int bi = redI[0][tid];
        #pragma unroll
        for (int ww = 1; ww < 4; ++ww) {
            float b2 = redS[ww][tid]; int bi2 = redI[ww][tid];
            if (b2 < b || (b2 == b && bi2 < bi)) { b = b2; bi = bi2; }
        }
        idx_out[pbase + tid] = bi;
    }
#undef ISSUE
#undef COMPUTE
#undef FOLD
}

// ---------------- residual/quant update (fp32, exact np order) ----------------
__global__ void k_update(const float* __restrict__ cb, const int* __restrict__ idx,
                         float* __restrict__ resid, float* __restrict__ quant) {
    int gid = blockIdx.x * blockDim.x + threadIdx.x;   // NPTS*32
    int n = gid >> 5, d4 = (gid & 31) * 4;
    int k = idx[n];
    float4 c = *(const float4*)(cb + (size_t)k * D + d4);
    size_t o = (size_t)n * D + d4;
    float4 r = *(const float4*)(resid + o);
    float4 q = *(const float4*)(quant + o);
    r.x = __fsub_rn(r.x, c.x); r.y = __fsub_rn(r.y, c.y);
    r.z = __fsub_rn(r.z, c.z); r.w = __fsub_rn(r.w, c.w);
    q.x = __fadd_rn(q.x, c.x); q.y = __fadd_rn(q.y, c.y);
    q.z = __fadd_rn(q.z, c.z); q.w = __fadd_rn(q.w, c.w);
    *(float4*)(resid + o) = r;
    *(float4*)(quant + o) = q;
}

// ---------------- out0 = fl(z + fl(q - z)) transposed; commitment partial ----------------
__global__ __launch_bounds__(256) void k_out0(const float* __restrict__ z,
                                              const float* __restrict__ quant,
                                              float* __restrict__ out0,
                                              double* __restrict__ csum) {
    __shared__ float xt[64][129];
    __shared__ double wsum[4];
    int b = blockIdx.x >> 6, st = blockIdx.x & 63;
    int s0 = st * 64;
    for (int it = 0; it < 8; ++it) {
        int flat = it * 256 + threadIdx.x;
        int sl = flat >> 5, dq = (flat & 31) * 4;
        float4 q = *(const float4*)(quant + (size_t)(b * SLEN + s0 + sl) * D + dq);
        xt[sl][dq] = q.x; xt[sl][dq + 1] = q.y;
        xt[sl][dq + 2] = q.z; xt[sl][dq + 3] = q.w;
    }
    __syncthreads();
    double v = 0.0;
    for (int it = 0; it < 32; ++it) {
        int flat = it * 256 + threadIdx.x;
        int d = flat >> 6, sl = flat & 63;
        size_t o = ((size_t)(b * D + d)) * SLEN + s0 + sl;
        float zz = z[o], qq = xt[sl][d];
        out0[o] = __fadd_rn(zz, __fsub_rn(qq, zz));
        float e = __fsub_rn(zz, qq);
        v += (double)e * (double)e;
    }
    for (int off = 32; off > 0; off >>= 1) v += __shfl_down(v, off, 64);
    int lane = threadIdx.x & 63, wv = threadIdx.x >> 6;
    if (lane == 0) wsum[wv] = v;
    __syncthreads();
    if (threadIdx.x == 0) {
        double tsum = wsum[0] + wsum[1] + wsum[2] + wsum[3];
        atomicAdd(csum, tsum);
    }
}

// ---------------- indices output as float ----------------
__global__ void k_outidx(const int* __restrict__ idx, float* __restrict__ out1) {
    int o = blockIdx.x * blockDim.x + threadIdx.x;   // NPTS*NQ
    int q = o & 7, n = o >> 3;
    out1[o] = (float)idx[q * NPTS + n];
}

// ---------------- histogram ----------------
__global__ void k_hist(const int* __restrict__ idx, int* __restrict__ hist) {
    int o = blockIdx.x * blockDim.x + threadIdx.x;   // NQ*NPTS (layout [q][n])
    int q = o >> 15;
    atomicAdd(&hist[q * KCODES + idx[o]], 1);
}

// ---------------- final scalars ----------------
__global__ __launch_bounds__(256) void k_final(const int* __restrict__ hist,
                                               const double* __restrict__ csum,
                                               float* __restrict__ outs) {
    __shared__ double sh[256];
    double perp = 0.0;
    for (int q = 0; q < NQ; ++q) {
        double h = 0.0;
        for (int k = threadIdx.x; k < KCODES; k += 256) {
            double p = (double)hist[q * KCODES + k] / (double)NPTS;
            h -= p * log(p + 1e-10);
        }
        sh[threadIdx.x] = h; __syncthreads();
        for (int off = 128; off > 0; off >>= 1) {
            if (threadIdx.x < off) sh[threadIdx.x] += sh[threadIdx.x + off];
            __syncthreads();
        }
        if (threadIdx.x == 0) perp += exp(sh[0]);
        __syncthreads();
    }
    if (threadIdx.x == 0) {
        outs[0] = (float)(*csum / (double)((size_t)NPTS * D));
        outs[1] = (float)(perp / (double)NQ);
    }
}

extern "C" void kernel_launch(void* const* d_in, const int* in_sizes, int n_in,
                              void* d_out, int out_size, void* d_ws, size_t ws_size,
                              hipStream_t stream) {
    const float* z  = (const float*)d_in[0];
    const float* cb = (const float*)d_in[1];
    float* out0 = (float*)d_out;                 // 4,194,304 floats [B,D,S]
    float* out1 = out0 + 4194304;                // 262,144 floats  [B,S,Q]
    float* outs = out1 + 262144;                 // 2 scalars

    char* w = (char*)d_ws;
    float* resid  = (float*)w;                           // 16,777,216 B
    float* quant  = (float*)(w + 16777216);              // 16,777,216 B
    int*   idx    = (int*)(w + 33554432);                //  1,048,576 B
    int*   hist   = (int*)(w + 34603008);                //     32,768 B
    double* csum  = (double*)(w + 34635776);             //         64 B
    float* c2f    = (float*)(w + 34635840);              //     32,768 B

    k_zero<<<32, 256, 0, stream>>>(hist, csum);
    k_c2<<<32, 256, 0, stream>>>(cb, c2f);
    k_init<<<512, 256, 0, stream>>>(z, resid, quant);

    for (int q = 0; q < NQ; ++q) {
        const float* cbq = cb + (size_t)q * KCODES * D;
        k_argmin<<<NPTS / TM, 256, 0, stream>>>(cbq, c2f + q * KCODES, resid,
                                                idx + q * NPTS);
        k_update<<<NPTS * 32 / 256, 256, 0, stream>>>(cbq, idx + q * NPTS,
                                                      resid, quant);
    }

    k_out0<<<512, 256, 0, stream>>>(z, quant, out0, csum);
    k_outidx<<<NPTS * NQ / 256, 256, 0, stream>>>(idx, out1);
    k_hist<<<NPTS * NQ / 256, 256, 0, stream>>>(idx, hist);
    k_final<<<1, 256, 0, stream>>>(hist, csum, outs);
}